// Round 7
// baseline (55.165 us; speedup 1.0000x reference)
//
#include <hip/hip_runtime.h>
#include <hip/hip_bf16.h>

// ---------------------------------------------------------------------------
// scores[y,x] = sum_h W2[h] * ( sum_{m,n} leaky( py[y,h,m,:].px[x,h,n,:] /8 ) ) / (nItem[x]*64)
// SINGLE kernel, 384 blocks (all co-resident; 2/CU):
//   blocks 0..71  : gallery+px prep   blocks 72..167: py prep
//   then per-XCD flush sync (8 wbl2 total, not 168 — r5's mistake), then att.
// Sync protocol:
//   producer: __syncthreads (vmcnt drain -> stores in local L2), t0 incs
//             prodcnt RELAXED.
//   every block t0: xcd = s_getreg(HW_REG_XCC_ID); first claimer per XCD
//             waits prodcnt==168, then ONE fetch_add(flushcnt, RELEASE, agent)
//             -> buffer_wbl2 sweeps ITS XCD's L2 (all same-XCD producers'
//             dirty frag lines, since their vmcnt drained before prodcnt inc).
//   all t0 spin flushcnt==8 relaxed (atomic loads hit coherence point), then
//             __syncthreads -> att. No consumer acquire needed: LLC is the
//             coherence point; consumer L2 lines are cold (r5 proved correct).
//   384 blocks >= 256 CUs -> every XCD hosts blocks -> flushcnt reaches 8.
//   flags (10 words) zeroed by a 64B memset node each replay.
// Fragment map (A and B of mfma_f32_16x16x32_bf16, same map):
//   lane l holds (rc=l&15, k=8*(l>>4)+i), i=0..7.  C/D: col=l&15, row=(l>>4)*4+j.
// py image: [y][h][mt(4)][kc(2)][lane(64)][i(8)]
// px image: [x][h][nt(3)][kc(2)][lane(64)][i(8)]
// ---------------------------------------------------------------------------

typedef short bf16x8 __attribute__((ext_vector_type(8)));
typedef float f32x4 __attribute__((ext_vector_type(4)));

#define NPROD 168u
#define NBLK  384
#define F_PRODCNT 0
#define F_FLUSHCNT 1
#define F_CLAIM 2   // 2..9

__device__ __forceinline__ unsigned short f2bf(float v) {
  __hip_bfloat16 b = __float2bfloat16(v);
  return *reinterpret_cast<unsigned short*>(&b);
}

__device__ __forceinline__ bf16x8 load8_cvt(const float* __restrict__ p) {
  f32x4 v0 = *reinterpret_cast<const f32x4*>(p);
  f32x4 v1 = *reinterpret_cast<const f32x4*>(p + 4);
  bf16x8 r;
  r[0] = (short)f2bf(v0[0]); r[1] = (short)f2bf(v0[1]);
  r[2] = (short)f2bf(v0[2]); r[3] = (short)f2bf(v0[3]);
  r[4] = (short)f2bf(v1[0]); r[5] = (short)f2bf(v1[1]);
  r[6] = (short)f2bf(v1[2]); r[7] = (short)f2bf(v1[3]);
  return r;
}

__global__ __launch_bounds__(256, 2) void k_fused(const float* __restrict__ x,
                                                  const float* __restrict__ y,
                                                  const float* __restrict__ Wp,
                                                  const float* __restrict__ W1,
                                                  const float* __restrict__ nItem,
                                                  const float* __restrict__ W2,
                                                  unsigned short* __restrict__ pyf,
                                                  unsigned short* __restrict__ pxf,
                                                  unsigned int* flags,
                                                  float* __restrict__ out) {
  __shared__ unsigned short w1f[8192];      // frag f=kc*8+nt: [f][lane][8]  16KB
  __shared__ unsigned short wpf[8192];      // quarter: g=kk*4+nt: [g][lane][8] 16KB
  __shared__ unsigned short gal[4][1152];   // per-wave 16 x 72 (padded)      9KB
  int t = threadIdx.x;
  int lane = t & 63, w = t >> 6;
  int b = blockIdx.x;

  // hoisted const reads (safe pre-sync: pure inputs)
  float w2h0 = W2[0], w2h1 = W2[1];
  int xi0 = (b & 15) * 6;
  float nI[6];
#pragma unroll
  for (int g = 0; g < 6; ++g) nI[g] = nItem[xi0 + g];

  // ======================= prep phase (producers only) =====================
  if (b < (int)NPROD) {
#pragma unroll
    for (int it = 0; it < 32; ++it) {
      int idx = it * 256 + t;                // over 64*128
      int k = idx >> 7, d = idx & 127;
      int l = (d & 15) + 16 * ((k >> 3) & 3);
      int f = (k >> 5) * 8 + (d >> 4);
      w1f[f * 512 + l * 8 + (k & 7)] = f2bf(W1[idx]);
    }
    if (b >= 72) {
      // ------------------------- py: yi = b - 72 ---------------------------
      __syncthreads();
      int yi = b - 72;
      const bf16x8* WF = reinterpret_cast<const bf16x8*>(w1f);
      int row0 = yi * 64 + w * 16 + (lane & 15);
      const float* yb = y + (size_t)row0 * 64 + 8 * (lane >> 4);
      bf16x8 a0 = load8_cvt(yb);
      bf16x8 a1 = load8_cvt(yb + 32);
      f32x4 acc[8];
#pragma unroll
      for (int nt = 0; nt < 8; ++nt) acc[nt] = (f32x4){0.f, 0.f, 0.f, 0.f};
#pragma unroll
      for (int nt = 0; nt < 8; ++nt) {
        acc[nt] = __builtin_amdgcn_mfma_f32_16x16x32_bf16(a0, WF[nt * 64 + lane], acc[nt], 0, 0, 0);
        acc[nt] = __builtin_amdgcn_mfma_f32_16x16x32_bf16(a1, WF[(8 + nt) * 64 + lane], acc[nt], 0, 0, 0);
      }
      int r_hi = (lane >> 4) * 4;
#pragma unroll
      for (int nt = 0; nt < 8; ++nt) {
        int d = nt * 16 + (lane & 15);
        int h = d >> 6, dd = d & 63;
        int kc = dd >> 5, q = (dd >> 3) & 3, i = dd & 7;
#pragma unroll
        for (int j = 0; j < 4; ++j) {
          int m = w * 16 + r_hi + j;
          int mt = m >> 4, rr = m & 15;
          size_t idx = ((size_t)((yi * 2 + h) * 8 + mt * 2 + kc)) * 512 + (rr + (q << 4)) * 8 + i;
          pyf[idx] = f2bf(acc[nt][j]);
        }
      }
    } else {
      // -------------------- gallery+px: 64 rows of x -----------------------
      int rowbase = b * 64;
      const bf16x8* WPF = reinterpret_cast<const bf16x8*>(wpf);
      const bf16x8* WF = reinterpret_cast<const bf16x8*>(w1f);
      int rloc = rowbase + w * 16 + (lane & 15);
      const float* xb = x + (size_t)rloc * 512 + 8 * (lane >> 4);
      f32x4 acc1[4];
#pragma unroll
      for (int nt = 0; nt < 4; ++nt) acc1[nt] = (f32x4){0.f, 0.f, 0.f, 0.f};
#pragma unroll
      for (int q = 0; q < 4; ++q) {          // K quarters of 128
        if (q) __syncthreads();              // protect previous quarter's reads
#pragma unroll
        for (int it = 0; it < 32; ++it) {
          int idx = it * 256 + t;            // over 128*64
          int kq = idx >> 6, c = idx & 63;
          int l = (c & 15) + 16 * ((kq >> 3) & 3);
          int g = ((kq >> 5) & 3) * 4 + (c >> 4);
          wpf[g * 512 + l * 8 + (kq & 7)] = f2bf(Wp[(q * 128 + kq) * 64 + c]);
        }
        __syncthreads();
#pragma unroll
        for (int kk = 0; kk < 4; ++kk) {
          int kc = q * 4 + kk;
          bf16x8 a = load8_cvt(xb + 32 * kc);
#pragma unroll
          for (int nt = 0; nt < 4; ++nt)
            acc1[nt] = __builtin_amdgcn_mfma_f32_16x16x32_bf16(a, WPF[(kk * 4 + nt) * 64 + lane], acc1[nt], 0, 0, 0);
        }
      }
      // gelu -> own-wave gal tile (same-wave LDS RAW, no barrier needed)
#pragma unroll
      for (int nt = 0; nt < 4; ++nt)
#pragma unroll
        for (int j = 0; j < 4; ++j) {
          float s = acc1[nt][j];
          float ge = 0.5f * s * (1.0f + erff(s * 0.70710678118654752f));
          int rl = (lane >> 4) * 4 + j;
          int c = nt * 16 + (lane & 15);
          gal[w][rl * 72 + c] = f2bf(ge);
        }
      const unsigned short* gp = &gal[w][(lane & 15) * 72 + 8 * (lane >> 4)];
      bf16x8 g0 = *reinterpret_cast<const bf16x8*>(gp);
      bf16x8 g1 = *reinterpret_cast<const bf16x8*>(gp + 32);
      f32x4 acc2[8];
#pragma unroll
      for (int nt = 0; nt < 8; ++nt) acc2[nt] = (f32x4){0.f, 0.f, 0.f, 0.f};
#pragma unroll
      for (int nt = 0; nt < 8; ++nt) {
        acc2[nt] = __builtin_amdgcn_mfma_f32_16x16x32_bf16(g0, WF[nt * 64 + lane], acc2[nt], 0, 0, 0);
        acc2[nt] = __builtin_amdgcn_mfma_f32_16x16x32_bf16(g1, WF[(8 + nt) * 64 + lane], acc2[nt], 0, 0, 0);
      }
      int r_hi = (lane >> 4) * 4;
#pragma unroll
      for (int nt = 0; nt < 8; ++nt) {
        int d = nt * 16 + (lane & 15);
        int h = d >> 6, dd = d & 63;
        int kc = dd >> 5, q2 = (dd >> 3) & 3, i = dd & 7;
#pragma unroll
        for (int j = 0; j < 4; ++j) {
          int row = rowbase + w * 16 + r_hi + j;
          int xi = row / 48, n = row % 48;
          int nt3 = n >> 4, rr = n & 15;
          size_t idx = ((size_t)((xi * 2 + h) * 6 + nt3 * 2 + kc)) * 512 + (rr + (q2 << 4)) * 8 + i;
          pxf[idx] = f2bf(acc2[nt][j]);
        }
      }
    }
  }

  // ================ per-XCD flush sync (8 wbl2 total) ======================
  __syncthreads();   // vmcnt(0) drain per wave -> producer stores are in local L2
  if (t == 0) {
    if (b < (int)NPROD)
      __hip_atomic_fetch_add(&flags[F_PRODCNT], 1u, __ATOMIC_RELAXED, __HIP_MEMORY_SCOPE_AGENT);
    unsigned xcd;
    asm volatile("s_getreg_b32 %0, hwreg(HW_REG_XCC_ID)" : "=s"(xcd));
    xcd &= 7u;
    if (__hip_atomic_fetch_add(&flags[F_CLAIM + xcd], 1u, __ATOMIC_RELAXED, __HIP_MEMORY_SCOPE_AGENT) == 0u) {
      // elected flusher for this XCD
      while (__hip_atomic_load(&flags[F_PRODCNT], __ATOMIC_RELAXED, __HIP_MEMORY_SCOPE_AGENT) != NPROD)
        __builtin_amdgcn_s_sleep(4);
      // RELEASE -> buffer_wbl2 sweeps THIS XCD's L2 (all producers here drained)
      __hip_atomic_fetch_add(&flags[F_FLUSHCNT], 1u, __ATOMIC_RELEASE, __HIP_MEMORY_SCOPE_AGENT);
    }
    while (__hip_atomic_load(&flags[F_FLUSHCNT], __ATOMIC_RELAXED, __HIP_MEMORY_SCOPE_AGENT) != 8u)
      __builtin_amdgcn_s_sleep(4);
  }
  __syncthreads();

  // ================================ att ====================================
  {
    int yi = (b >> 4) * 4 + w;
    const bf16x8* PA = reinterpret_cast<const bf16x8*>(pyf);
    const bf16x8* PB = reinterpret_cast<const bf16x8*>(pxf);

    f32x4 zero4 = {0.f, 0.f, 0.f, 0.f};
    asm volatile("" : "+v"(zero4));

    bf16x8 A8[16];                           // both heads: [h*8 + mt*2 + kc]
    size_t abase = (size_t)(yi * 2) * 512 + lane;
#pragma unroll
    for (int f = 0; f < 8; ++f) {
      A8[f]     = PA[abase + f * 64];
      A8[8 + f] = PA[abase + 512 + f * 64];
    }
    float c3h0 = 0.3f * w2h0, c7h0 = 0.7f * w2h0;
    float c3h1 = 0.3f * w2h1, c7h1 = 0.7f * w2h1;

    bf16x8 Bc[6], Bn[6];
    size_t bb0 = (size_t)((xi0 * 2 + 0) * 6) * 64 + lane;  // s=0: g=0,h=0
#pragma unroll
    for (int f = 0; f < 6; ++f) Bc[f] = PB[bb0 + f * 64];

    f32x4 res4[6];
#pragma unroll
    for (int g = 0; g < 6; ++g) res4[g] = (f32x4){0.f, 0.f, 0.f, 0.f};

#pragma unroll
    for (int s = 0; s < 12; ++s) {           // s = g*2 + h
      const int h = s & 1, g = s >> 1;
      if (s < 11) {                          // prefetch next step's B-frags
        const int s2 = s + 1, h2 = s2 & 1, g2 = s2 >> 1;
        size_t bb = (size_t)(((xi0 + g2) * 2 + h2) * 6) * 64 + lane;
#pragma unroll
        for (int f = 0; f < 6; ++f) Bn[f] = PB[bb + f * 64];
      }
      const float c3 = h ? c3h1 : c3h0;
      const float c7 = h ? c7h1 : c7h0;
#pragma unroll
      for (int nt = 0; nt < 3; ++nt)
#pragma unroll
        for (int mt = 0; mt < 4; ++mt) {
          f32x4 acc = __builtin_amdgcn_mfma_f32_16x16x32_bf16(A8[h * 8 + mt * 2], Bc[nt * 2], zero4, 0, 0, 0);
          acc = __builtin_amdgcn_mfma_f32_16x16x32_bf16(A8[h * 8 + mt * 2 + 1], Bc[nt * 2 + 1], acc, 0, 0, 0);
          f32x4 mx = {fmaxf(acc[0], 0.f), fmaxf(acc[1], 0.f), fmaxf(acc[2], 0.f), fmaxf(acc[3], 0.f)};
          res4[g] += acc * c3;
          res4[g] += mx * c7;
        }
#pragma unroll
      for (int f = 0; f < 6; ++f) Bc[f] = Bn[f];  // renamed by full unroll
    }

    float tot[6];
#pragma unroll
    for (int g = 0; g < 6; ++g)
      tot[g] = (res4[g][0] + res4[g][1]) + (res4[g][2] + res4[g][3]);
#pragma unroll
    for (int off = 32; off >= 1; off >>= 1)
#pragma unroll
      for (int g = 0; g < 6; ++g) tot[g] += __shfl_xor(tot[g], off, 64);
    if (lane == 0) {
#pragma unroll
      for (int g = 0; g < 6; ++g)
        out[yi * 96 + xi0 + g] = tot[g] / (512.0f * nI[g]);
    }
  }
}

// ---------------------------------------------------------------------------
extern "C" void kernel_launch(void* const* d_in, const int* in_sizes, int n_in,
                              void* d_out, int out_size, void* d_ws, size_t ws_size,
                              hipStream_t stream) {
  const float* x     = (const float*)d_in[0]; // [96,48,512]
  const float* y     = (const float*)d_in[1]; // [96,64,64]
  const float* nItem = (const float*)d_in[2]; // [96]
  const float* Wp    = (const float*)d_in[3]; // [512,64]
  const float* W1    = (const float*)d_in[4]; // [64,128]
  const float* W2    = (const float*)d_in[5]; // [2,1]
  float* out = (float*)d_out;                 // [96,96,1]

  unsigned short* pyf = (unsigned short*)d_ws;         // 786432 u16 (1.5MB)
  unsigned short* pxf = pyf + 786432;                  // 589824 u16 (1.125MB)
  unsigned int* flags = (unsigned int*)(pxf + 589824); // 16 u32

  hipMemsetAsync(flags, 0, 64, stream);                // flags := 0 each replay
  hipLaunchKernelGGL(k_fused, dim3(NBLK), dim3(256), 0, stream,
                     x, y, Wp, W1, nItem, W2, pyf, pxf, flags, out);
}